// Round 3
// baseline (219.651 us; speedup 1.0000x reference)
//
#include <hip/hip_runtime.h>

typedef __attribute__((ext_vector_type(8))) short bf16x8;
typedef __attribute__((ext_vector_type(4))) float f32x4;
typedef __attribute__((ext_vector_type(4))) unsigned short u16x4;

// ---------------- helpers ----------------

static __device__ __forceinline__ unsigned short f2bfu(float f) {
  union { float f; unsigned u; } v; v.f = f;
  return (unsigned short)((v.u + 0x7fffu + ((v.u >> 16) & 1u)) >> 16);  // RNE
}

static __device__ __forceinline__ void gload_lds16(const void* g, void* l) {
  // async global->LDS, 16B/lane; LDS dest = wave-uniform base + lane*16
  __builtin_amdgcn_global_load_lds(
      (const __attribute__((address_space(1))) unsigned int*)g,
      (__attribute__((address_space(3))) unsigned int*)l, 16, 0, 0);
}

// ---------------- prep: cast x to bf16 ----------------
__global__ __launch_bounds__(256) void k_cast_bf16(const float* __restrict__ in,
                                                   unsigned short* __restrict__ out) {
  int i = blockIdx.x * 256 + threadIdx.x;          // grid covers exactly n/4
  float4 v = ((const float4*)in)[i];
  u16x4 o = { f2bfu(v.x), f2bfu(v.y), f2bfu(v.z), f2bfu(v.w) };
  *(u16x4*)(out + (size_t)i * 4) = o;
}

// ---------------- zero mids ----------------
__global__ __launch_bounds__(256) void k_zero4(float4* __restrict__ p) {
  p[(size_t)blockIdx.x * 256 + threadIdx.x] = float4{0.f, 0.f, 0.f, 0.f};
}

// ---------------- prep: per-expert transpose+convert ----------------
// in:  f32  [z][R][C]   out: bf16 at  out + z*eoff + c*ostride + r
__global__ __launch_bounds__(256) void k_transpose_bf16(const float* __restrict__ in,
                                                        unsigned short* __restrict__ out,
                                                        int R, int C, int ostride, long eoff) {
  __shared__ float tile[32][33];
  int z = blockIdx.z;
  int c0 = blockIdx.x * 32, r0 = blockIdx.y * 32;
  const float* src = in + (size_t)z * R * C;
  unsigned short* dst = out + (size_t)z * eoff;
  int tx = threadIdx.x & 31, ty = threadIdx.x >> 5;   // 32 x 8
#pragma unroll
  for (int i = 0; i < 32; i += 8)
    tile[ty + i][tx] = src[(size_t)(r0 + ty + i) * C + (c0 + tx)];
  __syncthreads();
#pragma unroll
  for (int i = 0; i < 32; i += 8)
    dst[(size_t)(c0 + ty + i) * ostride + (r0 + tx)] = f2bfu(tile[tx][ty + i]);
}

// ---------------- router: logits, softmax-top8, combine weights ----------------
__global__ __launch_bounds__(64) void k_router(const float* __restrict__ x,
                                               const float* __restrict__ gw,
                                               float* __restrict__ combine,
                                               float* __restrict__ logits) {
  int t = blockIdx.x;
  int lane = threadIdx.x;
  const float* xr = x + (size_t)t * 1024;
  float acc[16];
#pragma unroll
  for (int e = 0; e < 16; ++e) acc[e] = 0.f;
  for (int h = lane; h < 1024; h += 64) {
    float xv = xr[h];
    const float4* gr = (const float4*)(gw + (size_t)h * 16);
#pragma unroll
    for (int q = 0; q < 4; ++q) {
      float4 g4 = gr[q];
      acc[q * 4 + 0] += xv * g4.x;
      acc[q * 4 + 1] += xv * g4.y;
      acc[q * 4 + 2] += xv * g4.z;
      acc[q * 4 + 3] += xv * g4.w;
    }
  }
#pragma unroll
  for (int e = 0; e < 16; ++e) {
#pragma unroll
    for (int off = 32; off > 0; off >>= 1)
      acc[e] += __shfl_xor(acc[e], off);
  }
  if (lane < 16) logits[(size_t)t * 16 + lane] = acc[lane];

  // top-8 of logits == top-8 of softmax (monotone); renormalized weights
  float m = acc[0];
#pragma unroll
  for (int e = 1; e < 16; ++e) m = fmaxf(m, acc[e]);
  unsigned sel = 0u;
  for (int k = 0; k < 8; ++k) {
    float best = -3.4e38f; int bi = 0;
#pragma unroll
    for (int e = 0; e < 16; ++e)
      if (!((sel >> e) & 1u) && acc[e] > best) { best = acc[e]; bi = e; }
    sel |= 1u << bi;
  }
  float s = 0.f;
#pragma unroll
  for (int e = 0; e < 16; ++e)
    if ((sel >> e) & 1u) s += expf(acc[e] - m);
  float inv = 1.f / s;
  if (lane < 16)
    combine[(size_t)t * 16 + lane] = ((sel >> lane) & 1u) ? expf(acc[lane] - m) * inv : 0.f;
}

// ---------------- scan: deterministic per-expert packed token lists ----------------
// block e: idxlist[e][slot] = token ids (ascending) with combine[t][e] != 0
__global__ __launch_bounds__(256) void k_scan(const float* __restrict__ combine,
                                              unsigned short* __restrict__ idxlist,
                                              int* __restrict__ counts) {
  __shared__ int wsum[4];
  const int e = blockIdx.x;
  const int tid = threadIdx.x;
  const int lane = tid & 63, w = tid >> 6;
  const int t0 = tid * 8;
  int flags = 0, cnt = 0;
#pragma unroll
  for (int j = 0; j < 8; ++j) {
    float c = combine[(size_t)(t0 + j) * 16 + e];
    if (c != 0.f) { flags |= 1 << j; ++cnt; }
  }
  int scan = cnt;                      // wave-inclusive scan
#pragma unroll
  for (int off = 1; off < 64; off <<= 1) {
    int v = __shfl_up(scan, off);
    if (lane >= off) scan += v;
  }
  if (lane == 63) wsum[w] = scan;
  __syncthreads();
  int base = 0;
  for (int i = 0; i < w; ++i) base += wsum[i];
  int pos = base + scan - cnt;         // exclusive prefix for this thread
  for (int j = 0; j < 8; ++j)
    if ((flags >> j) & 1) idxlist[e * 2048 + pos++] = (unsigned short)(t0 + j);
  if (tid == 255) counts[e] = base + scan;
}

// ---------------- sparse gather gate+up GEMM ----------------
// For expert e with Ne packed tokens: mid[t][e*512+i] = silu(x@wg)*(x@wu)*combine
// BM=128 packed slots, BN=64 (i), BK=32. 4 waves. A rows gathered via idxlist.
__global__ __launch_bounds__(256) void k_gateup(const unsigned short* __restrict__ xb,
                                                const unsigned short* __restrict__ wgt,
                                                const unsigned short* __restrict__ wut,
                                                const float* __restrict__ combine,
                                                const unsigned short* __restrict__ idxlist,
                                                const int* __restrict__ counts,
                                                unsigned short* __restrict__ mids) {
  const int e  = blockIdx.z;
  const int Ne = counts[e];
  const int m0 = blockIdx.x * 128;
  if (m0 >= Ne) return;                // expert has no tokens in this tile

  __shared__ alignas(16) char lds[16384];
  char* sA  = lds;           // 128x32 bf16 (rows = packed slots), 64B rows
  char* sBg = lds + 8192;    // 64x32 (rows = i)
  char* sBu = lds + 12288;

  const int i0 = blockIdx.y * 64;
  const int tid = threadIdx.x;
  const int lane = tid & 63;
  const int w = tid >> 6;
  const int wm = (w >> 1) * 64;
  const int wn = (w & 1) * 32;

  const unsigned short* wg = wgt + (size_t)e * (512 * 1024);
  const unsigned short* wu = wut + (size_t)e * (512 * 1024);

  const int srow = lane >> 2;                       // row within 16-row chunk
  const int slog = (lane & 3) ^ ((srow >> 1) & 3);  // pre-swizzled source slot

  // staging roles: w0 -> A rows 0-63, w1 -> A rows 64-127, w2 -> Bg, w3 -> Bu
  char* db;
  const unsigned short* wsrc = nullptr;
  int tj[4];
  if (w < 2) {
    db = sA + w * 4096;
#pragma unroll
    for (int j = 0; j < 4; ++j) {
      int slot = m0 + w * 64 + j * 16 + srow;
      slot = slot < Ne ? slot : Ne - 1;            // clamp: guarded in epilogue
      tj[j] = idxlist[e * 2048 + slot];
    }
  } else if (w == 2) { wsrc = wg + (size_t)(i0 + srow) * 1024 + slog * 8; db = sBg; }
  else               { wsrc = wu + (size_t)(i0 + srow) * 1024 + slog * 8; db = sBu; }

  const int r0 = lane & 15;
  const int gp16 = ((lane >> 4) ^ ((r0 >> 1) & 3)) << 4;  // swizzled read slot (bytes)
  const char* ap  = sA  + ((wm + r0) << 6) + gp16;
  const char* bgp = sBg + ((wn + r0) << 6) + gp16;
  const char* bup = sBu + ((wn + r0) << 6) + gp16;

  f32x4 accg[4][2], accu[4][2];
#pragma unroll
  for (int fm = 0; fm < 4; ++fm)
#pragma unroll
    for (int fn = 0; fn < 2; ++fn) {
      accg[fm][fn] = f32x4{0.f, 0.f, 0.f, 0.f};
      accu[fm][fn] = f32x4{0.f, 0.f, 0.f, 0.f};
    }

  for (int k0 = 0; k0 < 1024; k0 += 32) {
    if (w < 2) {
#pragma unroll
      for (int j = 0; j < 4; ++j)
        gload_lds16(xb + (size_t)tj[j] * 1024 + slog * 8 + k0, db + j * 1024);
    } else {
#pragma unroll
      for (int j = 0; j < 4; ++j)
        gload_lds16(wsrc + k0 + (size_t)j * (16 * 1024), db + j * 1024);
    }
    __syncthreads();
    bf16x8 a[4], bg[2], bu[2];
#pragma unroll
    for (int fm = 0; fm < 4; ++fm) a[fm] = *(const bf16x8*)(ap + fm * 1024);
#pragma unroll
    for (int fn = 0; fn < 2; ++fn) {
      bg[fn] = *(const bf16x8*)(bgp + fn * 1024);
      bu[fn] = *(const bf16x8*)(bup + fn * 1024);
    }
#pragma unroll
    for (int fm = 0; fm < 4; ++fm)
#pragma unroll
      for (int fn = 0; fn < 2; ++fn) {
        accg[fm][fn] = __builtin_amdgcn_mfma_f32_16x16x32_bf16(a[fm], bg[fn], accg[fm][fn], 0, 0, 0);
        accu[fm][fn] = __builtin_amdgcn_mfma_f32_16x16x32_bf16(a[fm], bu[fn], accu[fm][fn], 0, 0, 0);
      }
    __syncthreads();
  }

  const int gq = lane >> 4;
#pragma unroll
  for (int fm = 0; fm < 4; ++fm) {
#pragma unroll
    for (int jj = 0; jj < 4; ++jj) {
      int slot = m0 + wm + fm * 16 + gq * 4 + jj;
      if (slot >= Ne) continue;
      int t = idxlist[e * 2048 + slot];
      float cw = combine[(size_t)t * 16 + e];
#pragma unroll
      for (int fn = 0; fn < 2; ++fn) {
        float gv = accg[fm][fn][jj];
        float uv = accu[fm][fn][jj];
        float mv = gv / (1.f + __expf(-gv)) * uv * cw;
        mids[(size_t)t * 8192 + e * 512 + i0 + wn + fn * 16 + r0] = f2bfu(mv);
      }
    }
  }
}

// ---------------- down GEMM, split-K: part[z] = mid[:, z*2048:(z+1)*2048] @ WD[z slice]
// WD staged from wdt[h][k] (K-major). BM=128, BN=64, BK=32, grid 16x16x4 = 1024 blocks.
__global__ __launch_bounds__(256) void k_down(const unsigned short* __restrict__ mids,
                                              const unsigned short* __restrict__ wdt,
                                              float* __restrict__ part) {
  __shared__ alignas(16) char lds[12288];
  char* sA = lds;          // 128x32
  char* sB = lds + 8192;   // 64x32

  const int m0 = blockIdx.x * 128;
  const int h0 = blockIdx.y * 64;
  const int kz = blockIdx.z;             // split-K slice: K in [kz*2048, kz*2048+2048)
  const int tid = threadIdx.x;
  const int lane = tid & 63;
  const int w = tid >> 6;
  const int wm = (w >> 1) * 64;
  const int wn = (w & 1) * 32;

  const unsigned short* sb = nullptr;
  char* db = nullptr;
  if (w == 0)      { sb = mids + (size_t)m0 * 8192;        db = sA;        }
  else if (w == 1) { sb = mids + (size_t)(m0 + 64) * 8192; db = sA + 4096; }
  else if (w == 2) { sb = wdt + (size_t)h0 * 8192;         db = sB;        }
  const int srow = lane >> 2;
  const int slog = (lane & 3) ^ ((srow >> 1) & 3);
  const unsigned short* sg = sb ? (sb + (size_t)srow * 8192 + slog * 8) : nullptr;

  const int r0 = lane & 15;
  const int gp16 = ((lane >> 4) ^ ((r0 >> 1) & 3)) << 4;
  const char* ap = sA + ((wm + r0) << 6) + gp16;
  const char* bp = sB + ((wn + r0) << 6) + gp16;

  f32x4 acc[4][2];
#pragma unroll
  for (int fm = 0; fm < 4; ++fm)
#pragma unroll
    for (int fn = 0; fn < 2; ++fn) acc[fm][fn] = f32x4{0.f, 0.f, 0.f, 0.f};

  const int kbeg = kz * 2048, kend = kbeg + 2048;
  for (int k0 = kbeg; k0 < kend; k0 += 32) {
    if (sb) {
#pragma unroll
      for (int j = 0; j < 4; ++j)
        gload_lds16(sg + k0 + (size_t)j * (16 * 8192), db + j * 1024);
    }
    __syncthreads();
    bf16x8 a[4], b[2];
#pragma unroll
    for (int fm = 0; fm < 4; ++fm) a[fm] = *(const bf16x8*)(ap + fm * 1024);
#pragma unroll
    for (int fn = 0; fn < 2; ++fn) b[fn] = *(const bf16x8*)(bp + fn * 1024);
#pragma unroll
    for (int fm = 0; fm < 4; ++fm)
#pragma unroll
      for (int fn = 0; fn < 2; ++fn)
        acc[fm][fn] = __builtin_amdgcn_mfma_f32_16x16x32_bf16(a[fm], b[fn], acc[fm][fn], 0, 0, 0);
    __syncthreads();
  }

  float* pout = part + (size_t)kz * (2048 * 1024);
  const int gq = lane >> 4;
#pragma unroll
  for (int fm = 0; fm < 4; ++fm)
#pragma unroll
    for (int fn = 0; fn < 2; ++fn)
#pragma unroll
      for (int jj = 0; jj < 4; ++jj)
        pout[(size_t)(m0 + wm + fm * 16 + gq * 4 + jj) * 1024 + (h0 + wn + fn * 16 + r0)] =
            acc[fm][fn][jj];
}

// ---------------- reduce 4 split-K slices ----------------
__global__ __launch_bounds__(256) void k_reduce(const float* __restrict__ part,
                                                float* __restrict__ out) {
  int i = blockIdx.x * 256 + threadIdx.x;          // float4 index; grid covers 2048*1024/4
  const float4* p = (const float4*)part;
  float4 a = p[i];
  float4 b = p[i + 524288];
  float4 c = p[i + 2 * 524288];
  float4 d = p[i + 3 * 524288];
  float4 s = { a.x + b.x + c.x + d.x, a.y + b.y + c.y + d.y,
               a.z + b.z + c.z + d.z, a.w + b.w + c.w + d.w };
  ((float4*)out)[i] = s;
}

// ---------------- launch ----------------
extern "C" void kernel_launch(void* const* d_in, const int* in_sizes, int n_in,
                              void* d_out, int out_size, void* d_ws, size_t ws_size,
                              hipStream_t stream) {
  const float* x   = (const float*)d_in[0];  // [2048,1024]
  const float* gw  = (const float*)d_in[1];  // [1024,16]
  const float* wga = (const float*)d_in[2];  // [16,1024,512]
  const float* wup = (const float*)d_in[3];  // [16,1024,512]
  const float* wdo = (const float*)d_in[4];  // [16,512,1024]
  float* out = (float*)d_out;                       // [2048,1024]
  float* logits = out + (size_t)2048 * 1024;        // [2048,16]

  char* ws = (char*)d_ws;
  unsigned short* xb   = (unsigned short*)(ws + 0);         //  4 MB  x bf16
  unsigned short* wgt  = (unsigned short*)(ws + 4194304);   // 16 MB  [E][I][H]
  unsigned short* wut  = (unsigned short*)(ws + 20971520);  // 16 MB  [E][I][H]
  unsigned short* wdt  = (unsigned short*)(ws + 37748736);  // 16 MB  [H][E*I]
  unsigned short* mids = (unsigned short*)(ws + 54525952);  // 32 MB  [T][E*I]
  float* combine       = (float*)(ws + 88080384);           // 128 KB [T][E]
  unsigned short* idxl = (unsigned short*)(ws + 88211456);  // 64 KB  [E][T] packed lists
  int* counts          = (int*)(ws + 88276992);             // 64 B   [E]
  // split-K partials (32 MB) reuse the wgt/wut region — dead once k_gateup is done
  float* part          = (float*)(ws + 4194304);            // [4][2048][1024] f32

  k_cast_bf16<<<2048, 256, 0, stream>>>(x, xb);
  k_zero4<<<8192, 256, 0, stream>>>((float4*)mids);         // 32 MB of zeros
  k_transpose_bf16<<<dim3(16, 32, 16), 256, 0, stream>>>(wga, wgt, 1024, 512, 1024, 524288L);
  k_transpose_bf16<<<dim3(16, 32, 16), 256, 0, stream>>>(wup, wut, 1024, 512, 1024, 524288L);
  k_transpose_bf16<<<dim3(32, 16, 16), 256, 0, stream>>>(wdo, wdt, 512, 1024, 8192, 512L);
  k_router<<<2048, 64, 0, stream>>>(x, gw, combine, logits);
  k_scan<<<16, 256, 0, stream>>>(combine, idxl, counts);
  k_gateup<<<dim3(16, 8, 16), 256, 0, stream>>>(xb, wgt, wut, combine, idxl, counts, mids);
  k_down<<<dim3(16, 16, 4), 256, 0, stream>>>(mids, wdt, part);
  k_reduce<<<2048, 256, 0, stream>>>(part, out);
}

// Round 5
// 214.030 us; speedup vs baseline: 1.0263x; 1.0263x over previous
//
#include <hip/hip_runtime.h>

typedef __attribute__((ext_vector_type(8))) short bf16x8;
typedef __attribute__((ext_vector_type(4))) float f32x4;
typedef __attribute__((ext_vector_type(4))) unsigned short u16x4;

// ---------------- helpers ----------------

static __device__ __forceinline__ unsigned short f2bfu(float f) {
  union { float f; unsigned u; } v; v.f = f;
  return (unsigned short)((v.u + 0x7fffu + ((v.u >> 16) & 1u)) >> 16);  // RNE
}

static __device__ __forceinline__ float bfu2f(unsigned short u) {
  union { unsigned u; float f; } v; v.u = ((unsigned)u) << 16; return v.f;
}

static __device__ __forceinline__ void gload_lds16(const void* g, void* l) {
  // async global->LDS, 16B/lane; LDS dest = wave-uniform base + lane*16
  __builtin_amdgcn_global_load_lds(
      (const __attribute__((address_space(1))) unsigned int*)g,
      (__attribute__((address_space(3))) unsigned int*)l, 16, 0, 0);
}

// ---------------- prep: cast x to bf16 ----------------
__global__ __launch_bounds__(256) void k_cast_bf16(const float* __restrict__ in,
                                                   unsigned short* __restrict__ out) {
  int i = blockIdx.x * 256 + threadIdx.x;          // grid covers exactly n/4
  float4 v = ((const float4*)in)[i];
  u16x4 o = { f2bfu(v.x), f2bfu(v.y), f2bfu(v.z), f2bfu(v.w) };
  *(u16x4*)(out + (size_t)i * 4) = o;
}

// ---------------- prep: per-expert transpose+convert ----------------
// in:  f32  [z][R][C]   out: bf16 at  out + z*eoff + c*ostride + r
__global__ __launch_bounds__(256) void k_transpose_bf16(const float* __restrict__ in,
                                                        unsigned short* __restrict__ out,
                                                        int R, int C, int ostride, long eoff) {
  __shared__ float tile[32][33];
  int z = blockIdx.z;
  int c0 = blockIdx.x * 32, r0 = blockIdx.y * 32;
  const float* src = in + (size_t)z * R * C;
  unsigned short* dst = out + (size_t)z * eoff;
  int tx = threadIdx.x & 31, ty = threadIdx.x >> 5;   // 32 x 8
#pragma unroll
  for (int i = 0; i < 32; i += 8)
    tile[ty + i][tx] = src[(size_t)(r0 + ty + i) * C + (c0 + tx)];
  __syncthreads();
#pragma unroll
  for (int i = 0; i < 32; i += 8)
    dst[(size_t)(c0 + ty + i) * ostride + (r0 + tx)] = f2bfu(tile[tx][ty + i]);
}

// ---------------- router: logits, softmax-top8, combine weights ----------------
__global__ __launch_bounds__(64) void k_router(const float* __restrict__ x,
                                               const float* __restrict__ gw,
                                               float* __restrict__ combine,
                                               float* __restrict__ logits) {
  int t = blockIdx.x;
  int lane = threadIdx.x;
  const float* xr = x + (size_t)t * 1024;
  float acc[16];
#pragma unroll
  for (int e = 0; e < 16; ++e) acc[e] = 0.f;
  for (int h = lane; h < 1024; h += 64) {
    float xv = xr[h];
    const float4* gr = (const float4*)(gw + (size_t)h * 16);
#pragma unroll
    for (int q = 0; q < 4; ++q) {
      float4 g4 = gr[q];
      acc[q * 4 + 0] += xv * g4.x;
      acc[q * 4 + 1] += xv * g4.y;
      acc[q * 4 + 2] += xv * g4.z;
      acc[q * 4 + 3] += xv * g4.w;
    }
  }
#pragma unroll
  for (int e = 0; e < 16; ++e) {
#pragma unroll
    for (int off = 32; off > 0; off >>= 1)
      acc[e] += __shfl_xor(acc[e], off);
  }
  if (lane < 16) logits[(size_t)t * 16 + lane] = acc[lane];

  float m = acc[0];
#pragma unroll
  for (int e = 1; e < 16; ++e) m = fmaxf(m, acc[e]);
  unsigned sel = 0u;
  for (int k = 0; k < 8; ++k) {
    float best = -3.4e38f; int bi = 0;
#pragma unroll
    for (int e = 0; e < 16; ++e)
      if (!((sel >> e) & 1u) && acc[e] > best) { best = acc[e]; bi = e; }
    sel |= 1u << bi;
  }
  float s = 0.f;
#pragma unroll
  for (int e = 0; e < 16; ++e)
    if ((sel >> e) & 1u) s += expf(acc[e] - m);
  float inv = 1.f / s;
  if (lane < 16)
    combine[(size_t)t * 16 + lane] = ((sel >> lane) & 1u) ? expf(acc[lane] - m) * inv : 0.f;
}

// ---------------- scan: per-expert packed token lists + per-token slots ----------------
__global__ __launch_bounds__(256) void k_scan(const float* __restrict__ combine,
                                              unsigned short* __restrict__ idxlist,
                                              int* __restrict__ tokslot,
                                              int* __restrict__ counts) {
  __shared__ int wsum[4];
  const int e = blockIdx.x;
  const int tid = threadIdx.x;
  const int lane = tid & 63, w = tid >> 6;
  const int t0 = tid * 8;
  int flags = 0, cnt = 0;
#pragma unroll
  for (int j = 0; j < 8; ++j) {
    float c = combine[(size_t)(t0 + j) * 16 + e];
    if (c != 0.f) { flags |= 1 << j; ++cnt; }
  }
  int scan = cnt;                      // wave-inclusive scan
#pragma unroll
  for (int off = 1; off < 64; off <<= 1) {
    int v = __shfl_up(scan, off);
    if (lane >= off) scan += v;
  }
  if (lane == 63) wsum[w] = scan;
  __syncthreads();
  int base = 0;
  for (int i = 0; i < w; ++i) base += wsum[i];
  int pos = base + scan - cnt;         // exclusive prefix for this thread
  for (int j = 0; j < 8; ++j) {
    if ((flags >> j) & 1) {
      idxlist[e * 2048 + pos] = (unsigned short)(t0 + j);
      tokslot[(t0 + j) * 16 + e] = pos;
      ++pos;
    } else {
      tokslot[(t0 + j) * 16 + e] = -1;
    }
  }
  if (tid == 255) counts[e] = base + scan;
}

// ---------------- offsets: exclusive prefix of counts ----------------
__global__ __launch_bounds__(64) void k_offsets(const int* __restrict__ counts,
                                                int* __restrict__ ebase) {
  int lane = threadIdx.x;
  int c = (lane < 16) ? counts[lane] : 0;
  int s = c;
#pragma unroll
  for (int off = 1; off < 16; off <<= 1) {
    int v = __shfl_up(s, off);
    if (lane >= off) s += v;
  }
  if (lane < 16) ebase[lane] = s - c;
}

// ---------------- sparse gather gate+up GEMM (2-phase pipelined) ----------------
// mid_packed[ebase[e]+slot][i] = silu(x@wg)*(x@wu)  (UNWEIGHTED; cw applied in combine)
// BM=128 slots, BN=64 (i), BK=32, 32 k-steps. 4 waves. Double-buffered LDS.
__global__ __launch_bounds__(256) void k_gateup(const unsigned short* __restrict__ xb,
                                                const unsigned short* __restrict__ wgt,
                                                const unsigned short* __restrict__ wut,
                                                const unsigned short* __restrict__ idxlist,
                                                const int* __restrict__ counts,
                                                const int* __restrict__ ebase,
                                                unsigned short* __restrict__ midp) {
  const int e  = blockIdx.z;
  const int Ne = counts[e];
  const int m0 = blockIdx.x * 128;
  if (m0 >= Ne) return;

  __shared__ alignas(16) char lds[32768];   // 2 x (A 8K | Bg 4K | Bu 4K)

  const int i0 = blockIdx.y * 64;
  const int tid = threadIdx.x;
  const int lane = tid & 63;
  const int w = tid >> 6;
  const int wm = (w >> 1) * 64;
  const int wn = (w & 1) * 32;
  const int gb = ebase[e];

  const int srow = lane >> 2;                       // row within 16-row chunk
  const int slog = (lane & 3) ^ ((srow >> 1) & 3);  // pre-swizzled source slot

  const unsigned short* wsrc = nullptr;
  int tj[4];
  if (w < 2) {
#pragma unroll
    for (int j = 0; j < 4; ++j) {
      int slot = m0 + w * 64 + j * 16 + srow;
      slot = slot < Ne ? slot : Ne - 1;            // clamp: guarded in epilogue
      tj[j] = idxlist[e * 2048 + slot];
    }
  } else if (w == 2) {
    wsrc = wgt + (size_t)e * (512 * 1024) + (size_t)(i0 + srow) * 1024 + slog * 8;
  } else {
    wsrc = wut + (size_t)e * (512 * 1024) + (size_t)(i0 + srow) * 1024 + slog * 8;
  }

  auto stage = [&](int buf, int k0) {
    char* base = lds + buf * 16384;
    if (w < 2) {
      char* db = base + w * 4096;
#pragma unroll
      for (int j = 0; j < 4; ++j)
        gload_lds16(xb + (size_t)tj[j] * 1024 + slog * 8 + k0, db + j * 1024);
    } else {
      char* db = base + 8192 + (w - 2) * 4096;
#pragma unroll
      for (int j = 0; j < 4; ++j)
        gload_lds16(wsrc + k0 + (size_t)j * (16 * 1024), db + j * 1024);
    }
  };

  const int r0 = lane & 15;
  const int gp16 = ((lane >> 4) ^ ((r0 >> 1) & 3)) << 4;  // swizzled read slot (bytes)
  const int aoff  = ((wm + r0) << 6) + gp16;
  const int bgoff = 8192  + ((wn + r0) << 6) + gp16;
  const int buoff = 12288 + ((wn + r0) << 6) + gp16;

  f32x4 accg[4][2], accu[4][2];
#pragma unroll
  for (int fm = 0; fm < 4; ++fm)
#pragma unroll
    for (int fn = 0; fn < 2; ++fn) {
      accg[fm][fn] = f32x4{0.f, 0.f, 0.f, 0.f};
      accu[fm][fn] = f32x4{0.f, 0.f, 0.f, 0.f};
    }

  stage(0, 0);
  __syncthreads();
  for (int t = 0; t < 32; ++t) {
    const int cur = t & 1;
    if (t < 31) stage(cur ^ 1, (t + 1) * 32);      // prefetch overlaps compute
    const char* base = lds + cur * 16384;
    bf16x8 a[4], bg[2], bu[2];
#pragma unroll
    for (int fm = 0; fm < 4; ++fm) a[fm] = *(const bf16x8*)(base + aoff + fm * 1024);
#pragma unroll
    for (int fn = 0; fn < 2; ++fn) {
      bg[fn] = *(const bf16x8*)(base + bgoff + fn * 1024);
      bu[fn] = *(const bf16x8*)(base + buoff + fn * 1024);
    }
#pragma unroll
    for (int fm = 0; fm < 4; ++fm)
#pragma unroll
      for (int fn = 0; fn < 2; ++fn) {
        accg[fm][fn] = __builtin_amdgcn_mfma_f32_16x16x32_bf16(a[fm], bg[fn], accg[fm][fn], 0, 0, 0);
        accu[fm][fn] = __builtin_amdgcn_mfma_f32_16x16x32_bf16(a[fm], bu[fn], accu[fm][fn], 0, 0, 0);
      }
    __syncthreads();                               // drains vmcnt+lgkm (compiler)
  }

  const int gq = lane >> 4;
#pragma unroll
  for (int fm = 0; fm < 4; ++fm) {
#pragma unroll
    for (int jj = 0; jj < 4; ++jj) {
      int slot = m0 + wm + fm * 16 + gq * 4 + jj;
      if (slot >= Ne) continue;
#pragma unroll
      for (int fn = 0; fn < 2; ++fn) {
        float gv = accg[fm][fn][jj];
        float uv = accu[fm][fn][jj];
        float mv = gv / (1.f + __expf(-gv)) * uv;
        midp[(size_t)(gb + slot) * 512 + i0 + wn + fn * 16 + r0] = f2bfu(mv);
      }
    }
  }
}

// ---------------- grouped down GEMM (2-phase): dpk[gslot][h] = midp[gslot] @ wd[e]
// BM=128 slots, BN=64 (h), BK=32, 16 k-steps. wdt2[e][h][i] K-major.
__global__ __launch_bounds__(256) void k_down(const unsigned short* __restrict__ midp,
                                              const unsigned short* __restrict__ wdt2,
                                              const int* __restrict__ counts,
                                              const int* __restrict__ ebase,
                                              unsigned short* __restrict__ dpk) {
  const int e  = blockIdx.z;
  const int Ne = counts[e];
  const int m0 = blockIdx.x * 128;
  if (m0 >= Ne) return;

  __shared__ alignas(16) char lds[24576];   // 2 x (A 8K | B 4K)

  const int h0 = blockIdx.y * 64;
  const int tid = threadIdx.x;
  const int lane = tid & 63;
  const int w = tid >> 6;
  const int wm = (w >> 1) * 64;
  const int wn = (w & 1) * 32;
  const int gb = ebase[e];

  const int srow = lane >> 2;
  const int slog = (lane & 3) ^ ((srow >> 1) & 3);

  const unsigned short* bsrc = wdt2 + (size_t)e * (512 * 1024);

  auto stage = [&](int buf, int k0) {
    char* base = lds + buf * 12288;
    if (w < 2) {
      char* db = base + w * 4096;
#pragma unroll
      for (int j = 0; j < 4; ++j) {
        int slot = m0 + w * 64 + j * 16 + srow;
        slot = slot < Ne ? slot : Ne - 1;
        gload_lds16(midp + (size_t)(gb + slot) * 512 + slog * 8 + k0, db + j * 1024);
      }
    } else {
      // w2: B rows 0-31 (j=0,1), w3: B rows 32-63 (j=2,3)
#pragma unroll
      for (int jj = 0; jj < 2; ++jj) {
        int j = (w - 2) * 2 + jj;
        char* db = base + 8192 + j * 1024;
        gload_lds16(bsrc + (size_t)(h0 + j * 16 + srow) * 512 + slog * 8 + k0, db);
      }
    }
  };

  const int r0 = lane & 15;
  const int gp16 = ((lane >> 4) ^ ((r0 >> 1) & 3)) << 4;
  const int aoff = ((wm + r0) << 6) + gp16;
  const int boff = 8192 + ((wn + r0) << 6) + gp16;

  f32x4 acc[4][2];
#pragma unroll
  for (int fm = 0; fm < 4; ++fm)
#pragma unroll
    for (int fn = 0; fn < 2; ++fn) acc[fm][fn] = f32x4{0.f, 0.f, 0.f, 0.f};

  stage(0, 0);
  __syncthreads();
  for (int t = 0; t < 16; ++t) {
    const int cur = t & 1;
    if (t < 15) stage(cur ^ 1, (t + 1) * 32);
    const char* base = lds + cur * 12288;
    bf16x8 a[4], b[2];
#pragma unroll
    for (int fm = 0; fm < 4; ++fm) a[fm] = *(const bf16x8*)(base + aoff + fm * 1024);
#pragma unroll
    for (int fn = 0; fn < 2; ++fn) b[fn] = *(const bf16x8*)(base + boff + fn * 1024);
#pragma unroll
    for (int fm = 0; fm < 4; ++fm)
#pragma unroll
      for (int fn = 0; fn < 2; ++fn)
        acc[fm][fn] = __builtin_amdgcn_mfma_f32_16x16x32_bf16(a[fm], b[fn], acc[fm][fn], 0, 0, 0);
    __syncthreads();
  }

  const int gq = lane >> 4;
#pragma unroll
  for (int fm = 0; fm < 4; ++fm)
#pragma unroll
    for (int jj = 0; jj < 4; ++jj) {
      int slot = m0 + wm + fm * 16 + gq * 4 + jj;
      if (slot >= Ne) continue;
#pragma unroll
      for (int fn = 0; fn < 2; ++fn)
        dpk[(size_t)(gb + slot) * 1024 + h0 + wn + fn * 16 + r0] = f2bfu(acc[fm][fn][jj]);
    }
}

// ---------------- combine: out[t] = sum_e cw[t][e] * dpk[ebase[e]+slot(t,e)] ----------------
// 128 threads x 8 floats = exactly one 1024-float row.
__global__ __launch_bounds__(128) void k_combine(const unsigned short* __restrict__ dpk,
                                                 const int* __restrict__ tokslot,
                                                 const int* __restrict__ ebase,
                                                 const float* __restrict__ combine,
                                                 float* __restrict__ out) {
  __shared__ int gsl[16];
  __shared__ float cws[16];
  const int t = blockIdx.x;
  const int tid = threadIdx.x;
  if (tid < 16) {
    int sl = tokslot[t * 16 + tid];
    gsl[tid] = (sl >= 0) ? ebase[tid] + sl : -1;
    cws[tid] = combine[(size_t)t * 16 + tid];
  }
  __syncthreads();
  float av[8];
#pragma unroll
  for (int j = 0; j < 8; ++j) av[j] = 0.f;
#pragma unroll
  for (int e = 0; e < 16; ++e) {
    int g = gsl[e];
    if (g < 0) continue;
    float cw = cws[e];
    bf16x8 v = *(const bf16x8*)(dpk + (size_t)g * 1024 + tid * 8);
#pragma unroll
    for (int j = 0; j < 8; ++j) av[j] += cw * bfu2f((unsigned short)v[j]);
  }
  float4 lo = { av[0], av[1], av[2], av[3] };
  float4 hi = { av[4], av[5], av[6], av[7] };
  float4* op = (float4*)(out + (size_t)t * 1024 + tid * 8);
  op[0] = lo;
  op[1] = hi;
}

// ---------------- launch ----------------
extern "C" void kernel_launch(void* const* d_in, const int* in_sizes, int n_in,
                              void* d_out, int out_size, void* d_ws, size_t ws_size,
                              hipStream_t stream) {
  const float* x   = (const float*)d_in[0];  // [2048,1024]
  const float* gw  = (const float*)d_in[1];  // [1024,16]
  const float* wga = (const float*)d_in[2];  // [16,1024,512]
  const float* wup = (const float*)d_in[3];  // [16,1024,512]
  const float* wdo = (const float*)d_in[4];  // [16,512,1024]
  float* out = (float*)d_out;                       // [2048,1024]
  float* logits = out + (size_t)2048 * 1024;        // [2048,16]

  char* ws = (char*)d_ws;
  unsigned short* xb   = (unsigned short*)(ws + 0);         //  4 MB  x bf16
  unsigned short* wgt  = (unsigned short*)(ws + 4194304);   // 16 MB  [E][I][H]
  unsigned short* wut  = (unsigned short*)(ws + 20971520);  // 16 MB  [E][I][H]
  unsigned short* wdt2 = (unsigned short*)(ws + 37748736);  // 16 MB  [E][H][I]
  unsigned short* midp = (unsigned short*)(ws + 54525952);  // 16 MB  [16384][512] packed
  float* combine       = (float*)(ws + 71303168);           // 128 KB [T][E]
  int* tokslot         = (int*)(ws + 71434240);             // 128 KB [T][E]
  unsigned short* idxl = (unsigned short*)(ws + 71565312);  // 64 KB  [E][2048]
  int* counts          = (int*)(ws + 71630848);             // 64 B
  int* ebase           = (int*)(ws + 71630912);             // 64 B
  // down_packed bf16 [16384][1024] = 32 MB: reuses wgt+wut (dead after gateup)
  unsigned short* dpk  = (unsigned short*)(ws + 4194304);

  k_cast_bf16<<<2048, 256, 0, stream>>>(x, xb);
  k_transpose_bf16<<<dim3(16, 32, 16), 256, 0, stream>>>(wga, wgt, 1024, 512, 1024, 524288L);
  k_transpose_bf16<<<dim3(16, 32, 16), 256, 0, stream>>>(wup, wut, 1024, 512, 1024, 524288L);
  k_transpose_bf16<<<dim3(32, 16, 16), 256, 0, stream>>>(wdo, wdt2, 512, 1024, 512, 524288L);
  k_router<<<2048, 64, 0, stream>>>(x, gw, combine, logits);
  k_scan<<<16, 256, 0, stream>>>(combine, idxl, tokslot, counts);
  k_offsets<<<1, 64, 0, stream>>>(counts, ebase);
  k_gateup<<<dim3(16, 8, 16), 256, 0, stream>>>(xb, wgt, wut, idxl, counts, ebase, midp);
  k_down<<<dim3(16, 16, 16), 256, 0, stream>>>(midp, wdt2, counts, ebase, dpk);
  k_combine<<<2048, 128, 0, stream>>>(dpk, tokslot, ebase, combine, out);
}

// Round 6
// 153.059 us; speedup vs baseline: 1.4351x; 1.3983x over previous
//
#include <hip/hip_runtime.h>

typedef __attribute__((ext_vector_type(8))) short bf16x8;
typedef __attribute__((ext_vector_type(4))) float f32x4;
typedef __attribute__((ext_vector_type(4))) unsigned short u16x4;

// ---------------- helpers ----------------

static __device__ __forceinline__ unsigned short f2bfu(float f) {
  union { float f; unsigned u; } v; v.f = f;
  return (unsigned short)((v.u + 0x7fffu + ((v.u >> 16) & 1u)) >> 16);  // RNE
}

static __device__ __forceinline__ float bfu2f(unsigned short u) {
  union { unsigned u; float f; } v; v.u = ((unsigned)u) << 16; return v.f;
}

static __device__ __forceinline__ void gload_lds16(const void* g, void* l) {
  __builtin_amdgcn_global_load_lds(
      (const __attribute__((address_space(1))) unsigned int*)g,
      (__attribute__((address_space(3))) unsigned int*)l, 16, 0, 0);
}

// ---------------- prep: cast x to bf16 ----------------
__global__ __launch_bounds__(256) void k_cast_bf16(const float* __restrict__ in,
                                                   unsigned short* __restrict__ out) {
  int i = blockIdx.x * 256 + threadIdx.x;
  float4 v = ((const float4*)in)[i];
  u16x4 o = { f2bfu(v.x), f2bfu(v.y), f2bfu(v.z), f2bfu(v.w) };
  *(u16x4*)(out + (size_t)i * 4) = o;
}

// ---------------- prep: 64x64 vectorized transpose+convert ----------------
// in: f32 [z][R][C]   out: bf16 at out + z*eoff + c*ostride + r
__global__ __launch_bounds__(256) void k_transpose64(const float* __restrict__ in,
                                                     unsigned short* __restrict__ out,
                                                     int R, int C, int ostride, long eoff) {
  __shared__ float tile[64][65];
  int z = blockIdx.z;
  int c0 = blockIdx.x * 64, r0 = blockIdx.y * 64;
  const float* src = in + (size_t)z * R * C;
  unsigned short* dst = out + (size_t)z * eoff;
  int cc = (threadIdx.x & 15) * 4, rr = threadIdx.x >> 4;   // 16x4 cols, 16 rows/iter
#pragma unroll
  for (int i = 0; i < 4; ++i) {
    float4 v = *(const float4*)(src + (size_t)(r0 + rr + i * 16) * C + c0 + cc);
    tile[rr + i * 16][cc + 0] = v.x; tile[rr + i * 16][cc + 1] = v.y;
    tile[rr + i * 16][cc + 2] = v.z; tile[rr + i * 16][cc + 3] = v.w;
  }
  __syncthreads();
#pragma unroll
  for (int i = 0; i < 4; ++i) {
    int oc = rr + i * 16;
    u16x4 o = { f2bfu(tile[cc + 0][oc]), f2bfu(tile[cc + 1][oc]),
                f2bfu(tile[cc + 2][oc]), f2bfu(tile[cc + 3][oc]) };
    *(u16x4*)(dst + (size_t)(c0 + oc) * ostride + r0 + cc) = o;
  }
}

// ---------------- router ----------------
__global__ __launch_bounds__(64) void k_router(const float* __restrict__ x,
                                               const float* __restrict__ gw,
                                               float* __restrict__ combine,
                                               float* __restrict__ logits) {
  int t = blockIdx.x;
  int lane = threadIdx.x;
  const float* xr = x + (size_t)t * 1024;
  float acc[16];
#pragma unroll
  for (int e = 0; e < 16; ++e) acc[e] = 0.f;
  for (int h = lane; h < 1024; h += 64) {
    float xv = xr[h];
    const float4* gr = (const float4*)(gw + (size_t)h * 16);
#pragma unroll
    for (int q = 0; q < 4; ++q) {
      float4 g4 = gr[q];
      acc[q * 4 + 0] += xv * g4.x;
      acc[q * 4 + 1] += xv * g4.y;
      acc[q * 4 + 2] += xv * g4.z;
      acc[q * 4 + 3] += xv * g4.w;
    }
  }
#pragma unroll
  for (int e = 0; e < 16; ++e) {
#pragma unroll
    for (int off = 32; off > 0; off >>= 1)
      acc[e] += __shfl_xor(acc[e], off);
  }
  if (lane < 16) logits[(size_t)t * 16 + lane] = acc[lane];

  float m = acc[0];
#pragma unroll
  for (int e = 1; e < 16; ++e) m = fmaxf(m, acc[e]);
  unsigned sel = 0u;
  for (int k = 0; k < 8; ++k) {
    float best = -3.4e38f; int bi = 0;
#pragma unroll
    for (int e = 0; e < 16; ++e)
      if (!((sel >> e) & 1u) && acc[e] > best) { best = acc[e]; bi = e; }
    sel |= 1u << bi;
  }
  float s = 0.f;
#pragma unroll
  for (int e = 0; e < 16; ++e)
    if ((sel >> e) & 1u) s += expf(acc[e] - m);
  float inv = 1.f / s;
  if (lane < 16)
    combine[(size_t)t * 16 + lane] = ((sel >> lane) & 1u) ? expf(acc[lane] - m) * inv : 0.f;
}

// ---------------- scan ----------------
__global__ __launch_bounds__(256) void k_scan(const float* __restrict__ combine,
                                              unsigned short* __restrict__ idxlist,
                                              int* __restrict__ tokslot,
                                              int* __restrict__ counts) {
  __shared__ int wsum[4];
  const int e = blockIdx.x;
  const int tid = threadIdx.x;
  const int lane = tid & 63, w = tid >> 6;
  const int t0 = tid * 8;
  int flags = 0, cnt = 0;
#pragma unroll
  for (int j = 0; j < 8; ++j) {
    float c = combine[(size_t)(t0 + j) * 16 + e];
    if (c != 0.f) { flags |= 1 << j; ++cnt; }
  }
  int scan = cnt;
#pragma unroll
  for (int off = 1; off < 64; off <<= 1) {
    int v = __shfl_up(scan, off);
    if (lane >= off) scan += v;
  }
  if (lane == 63) wsum[w] = scan;
  __syncthreads();
  int base = 0;
  for (int i = 0; i < w; ++i) base += wsum[i];
  int pos = base + scan - cnt;
  for (int j = 0; j < 8; ++j) {
    if ((flags >> j) & 1) {
      idxlist[e * 2048 + pos] = (unsigned short)(t0 + j);
      tokslot[(t0 + j) * 16 + e] = pos;
      ++pos;
    } else {
      tokslot[(t0 + j) * 16 + e] = -1;
    }
  }
  if (tid == 255) counts[e] = base + scan;
}

// ---------------- offsets ----------------
__global__ __launch_bounds__(64) void k_offsets(const int* __restrict__ counts,
                                                int* __restrict__ ebase) {
  int lane = threadIdx.x;
  int c = (lane < 16) ? counts[lane] : 0;
  int s = c;
#pragma unroll
  for (int off = 1; off < 16; off <<= 1) {
    int v = __shfl_up(s, off);
    if (lane >= off) s += v;
  }
  if (lane < 16) ebase[lane] = s - c;
}

// ---------------- sparse gather gate+up GEMM ----------------
// BM=256 slots, BN=64 (i), BK=32, 32 k-steps, 8 waves (512 thr), 2-phase dbuf.
// 1-D grid 1024, logical order: m fastest, then i, then e; XCD-swizzled.
__global__ __launch_bounds__(512) void k_gateup(const unsigned short* __restrict__ xb,
                                                const unsigned short* __restrict__ wgt,
                                                const unsigned short* __restrict__ wut,
                                                const unsigned short* __restrict__ idxlist,
                                                const int* __restrict__ counts,
                                                const int* __restrict__ ebase,
                                                unsigned short* __restrict__ midp) {
  const int lb = (int)(blockIdx.x & 7) * 128 + (int)(blockIdx.x >> 3);
  const int mt = lb & 7, it = (lb >> 3) & 7, e = lb >> 6;
  const int Ne = counts[e];
  const int m0 = mt * 256;
  if (m0 >= Ne) return;
  const int i0 = it * 64;

  __shared__ alignas(16) char lds[49152];   // 2 x (A 16K | Bg 4K | Bu 4K)

  const int tid = threadIdx.x;
  const int lane = tid & 63;
  const int w = tid >> 6;                   // 0..7
  const int wm = (w >> 1) * 64;             // 4 wave-rows
  const int wn = (w & 1) * 32;              // 2 wave-cols
  const int gb = ebase[e];

  const int crow = lane >> 2;                       // row within 16-row chunk
  const int slog = (lane & 3) ^ ((crow >> 1) & 3);  // pre-swizzled source 16B slot

  const unsigned short* wge = wgt + (size_t)e * (512 * 1024);
  const unsigned short* wue = wut + (size_t)e * (512 * 1024);

  // 24 chunks of 1KB per buffer: 0-15 A (rows 16c..), 16-19 Bg, 20-23 Bu. 3 chunks/wave.
  const unsigned short* gsrc[3];
  int loff[3];
#pragma unroll
  for (int q = 0; q < 3; ++q) {
    int c = 3 * w + q;
    loff[q] = c * 1024;
    if (c < 16) {
      int slot = m0 + c * 16 + crow;
      slot = slot < Ne ? slot : Ne - 1;             // clamp: guarded in epilogue
      gsrc[q] = xb + (size_t)idxlist[e * 2048 + slot] * 1024 + slog * 8;
    } else if (c < 20) {
      gsrc[q] = wge + (size_t)(i0 + (c - 16) * 16 + crow) * 1024 + slog * 8;
    } else {
      gsrc[q] = wue + (size_t)(i0 + (c - 20) * 16 + crow) * 1024 + slog * 8;
    }
  }

  auto stage = [&](int buf, int k0) {
    char* base = lds + buf * 24576;
#pragma unroll
    for (int q = 0; q < 3; ++q)
      gload_lds16(gsrc[q] + k0, base + loff[q]);
  };

  const int r0 = lane & 15;
  const int gp16 = ((lane >> 4) ^ ((r0 >> 1) & 3)) << 4;
  const int aoff  = ((wm + r0) << 6) + gp16;
  const int bgoff = 16384 + ((wn + r0) << 6) + gp16;
  const int buoff = 20480 + ((wn + r0) << 6) + gp16;

  f32x4 accg[4][2], accu[4][2];
#pragma unroll
  for (int fm = 0; fm < 4; ++fm)
#pragma unroll
    for (int fn = 0; fn < 2; ++fn) {
      accg[fm][fn] = f32x4{0.f, 0.f, 0.f, 0.f};
      accu[fm][fn] = f32x4{0.f, 0.f, 0.f, 0.f};
    }

  stage(0, 0);
  __syncthreads();
  for (int t = 0; t < 32; ++t) {
    const int cur = t & 1;
    if (t < 31) stage(cur ^ 1, (t + 1) * 32);
    const char* base = lds + cur * 24576;
    bf16x8 a[4], bg[2], bu[2];
#pragma unroll
    for (int fm = 0; fm < 4; ++fm) a[fm] = *(const bf16x8*)(base + aoff + fm * 1024);
#pragma unroll
    for (int fn = 0; fn < 2; ++fn) {
      bg[fn] = *(const bf16x8*)(base + bgoff + fn * 1024);
      bu[fn] = *(const bf16x8*)(base + buoff + fn * 1024);
    }
#pragma unroll
    for (int fm = 0; fm < 4; ++fm)
#pragma unroll
      for (int fn = 0; fn < 2; ++fn) {
        accg[fm][fn] = __builtin_amdgcn_mfma_f32_16x16x32_bf16(a[fm], bg[fn], accg[fm][fn], 0, 0, 0);
        accu[fm][fn] = __builtin_amdgcn_mfma_f32_16x16x32_bf16(a[fm], bu[fn], accu[fm][fn], 0, 0, 0);
      }
    __syncthreads();
  }

  const int gq = lane >> 4;
#pragma unroll
  for (int fm = 0; fm < 4; ++fm) {
#pragma unroll
    for (int jj = 0; jj < 4; ++jj) {
      int slot = m0 + wm + fm * 16 + gq * 4 + jj;
      if (slot >= Ne) continue;
#pragma unroll
      for (int fn = 0; fn < 2; ++fn) {
        float gv = accg[fm][fn][jj];
        float uv = accu[fm][fn][jj];
        float mv = gv / (1.f + __expf(-gv)) * uv;
        midp[(size_t)(gb + slot) * 512 + i0 + wn + fn * 16 + r0] = f2bfu(mv);
      }
    }
  }
}

// ---------------- grouped down GEMM ----------------
// BM=256 slots, BN=64 (h), BK=32, 16 k-steps, 8 waves. dpk[gslot][h] bf16.
// 1-D grid 2048, logical m fastest, then h (16), then e; XCD-swizzled.
__global__ __launch_bounds__(512) void k_down(const unsigned short* __restrict__ midp,
                                              const unsigned short* __restrict__ wdt2,
                                              const int* __restrict__ counts,
                                              const int* __restrict__ ebase,
                                              unsigned short* __restrict__ dpk) {
  const int lb = (int)(blockIdx.x & 7) * 256 + (int)(blockIdx.x >> 3);
  const int mt = lb & 7, ht = (lb >> 3) & 15, e = lb >> 7;
  const int Ne = counts[e];
  const int m0 = mt * 256;
  if (m0 >= Ne) return;
  const int h0 = ht * 64;

  __shared__ alignas(16) char lds[40960];   // 2 x (A 16K | B 4K)

  const int tid = threadIdx.x;
  const int lane = tid & 63;
  const int w = tid >> 6;
  const int wm = (w >> 1) * 64;
  const int wn = (w & 1) * 32;
  const int gb = ebase[e];

  const int crow = lane >> 2;
  const int slog = (lane & 3) ^ ((crow >> 1) & 3);

  const unsigned short* bsrc = wdt2 + (size_t)e * (512 * 1024);

  // 20 chunks/buffer: A chunks {w, 8+w} per wave; B chunk 16+(w-4) for w>=4.
  const unsigned short* gsrcA[2];
  int loffA[2];
#pragma unroll
  for (int q = 0; q < 2; ++q) {
    int c = q * 8 + w;
    loffA[q] = c * 1024;
    int slot = m0 + c * 16 + crow;
    slot = slot < Ne ? slot : Ne - 1;
    gsrcA[q] = midp + (size_t)(gb + slot) * 512 + slog * 8;
  }
  const unsigned short* gsrcB = nullptr;
  int loffB = 0;
  if (w >= 4) {
    loffB = 16384 + (w - 4) * 1024;
    gsrcB = bsrc + (size_t)(h0 + (w - 4) * 16 + crow) * 512 + slog * 8;
  }

  auto stage = [&](int buf, int k0) {
    char* base = lds + buf * 20480;
#pragma unroll
    for (int q = 0; q < 2; ++q)
      gload_lds16(gsrcA[q] + k0, base + loffA[q]);
    if (gsrcB) gload_lds16(gsrcB + k0, base + loffB);
  };

  const int r0 = lane & 15;
  const int gp16 = ((lane >> 4) ^ ((r0 >> 1) & 3)) << 4;
  const int aoff = ((wm + r0) << 6) + gp16;
  const int boff = 16384 + ((wn + r0) << 6) + gp16;

  f32x4 acc[4][2];
#pragma unroll
  for (int fm = 0; fm < 4; ++fm)
#pragma unroll
    for (int fn = 0; fn < 2; ++fn) acc[fm][fn] = f32x4{0.f, 0.f, 0.f, 0.f};

  stage(0, 0);
  __syncthreads();
  for (int t = 0; t < 16; ++t) {
    const int cur = t & 1;
    if (t < 15) stage(cur ^ 1, (t + 1) * 32);
    const char* base = lds + cur * 20480;
    bf16x8 a[4], b[2];
#pragma unroll
    for (int fm = 0; fm < 4; ++fm) a[fm] = *(const bf16x8*)(base + aoff + fm * 1024);
#pragma unroll
    for (int fn = 0; fn < 2; ++fn) b[fn] = *(const bf16x8*)(base + boff + fn * 1024);
#pragma unroll
    for (int fm = 0; fm < 4; ++fm)
#pragma unroll
      for (int fn = 0; fn < 2; ++fn)
        acc[fm][fn] = __builtin_amdgcn_mfma_f32_16x16x32_bf16(a[fm], b[fn], acc[fm][fn], 0, 0, 0);
    __syncthreads();
  }

  const int gq = lane >> 4;
#pragma unroll
  for (int fm = 0; fm < 4; ++fm)
#pragma unroll
    for (int jj = 0; jj < 4; ++jj) {
      int slot = m0 + wm + fm * 16 + gq * 4 + jj;
      if (slot >= Ne) continue;
#pragma unroll
      for (int fn = 0; fn < 2; ++fn)
        dpk[(size_t)(gb + slot) * 1024 + h0 + wn + fn * 16 + r0] = f2bfu(acc[fm][fn][jj]);
    }
}

// ---------------- combine: out[t] = sum_e cw[t][e] * dpk row ----------------
__global__ __launch_bounds__(128) void k_combine(const unsigned short* __restrict__ dpk,
                                                 const int* __restrict__ tokslot,
                                                 const int* __restrict__ ebase,
                                                 const float* __restrict__ combine,
                                                 float* __restrict__ out) {
  __shared__ int gsl[16];
  __shared__ float cws[16];
  const int t = blockIdx.x;
  const int tid = threadIdx.x;
  if (tid < 16) {
    int sl = tokslot[t * 16 + tid];
    gsl[tid] = (sl >= 0) ? ebase[tid] + sl : -1;
    cws[tid] = combine[(size_t)t * 16 + tid];
  }
  __syncthreads();
  float av[8];
#pragma unroll
  for (int j = 0; j < 8; ++j) av[j] = 0.f;
#pragma unroll
  for (int e = 0; e < 16; ++e) {
    int g = gsl[e];
    if (g < 0) continue;
    float cw = cws[e];
    bf16x8 v = *(const bf16x8*)(dpk + (size_t)g * 1024 + tid * 8);
#pragma unroll
    for (int j = 0; j < 8; ++j) av[j] += cw * bfu2f((unsigned short)v[j]);
  }
  float4 lo = { av[0], av[1], av[2], av[3] };
  float4 hi = { av[4], av[5], av[6], av[7] };
  float4* op = (float4*)(out + (size_t)t * 1024 + tid * 8);
  op[0] = lo;
  op[1] = hi;
}

// ---------------- launch ----------------
extern "C" void kernel_launch(void* const* d_in, const int* in_sizes, int n_in,
                              void* d_out, int out_size, void* d_ws, size_t ws_size,
                              hipStream_t stream) {
  const float* x   = (const float*)d_in[0];  // [2048,1024]
  const float* gw  = (const float*)d_in[1];  // [1024,16]
  const float* wga = (const float*)d_in[2];  // [16,1024,512]
  const float* wup = (const float*)d_in[3];  // [16,1024,512]
  const float* wdo = (const float*)d_in[4];  // [16,512,1024]
  float* out = (float*)d_out;                       // [2048,1024]
  float* logits = out + (size_t)2048 * 1024;        // [2048,16]

  char* ws = (char*)d_ws;
  unsigned short* xb   = (unsigned short*)(ws + 0);         //  4 MB
  unsigned short* wgt  = (unsigned short*)(ws + 4194304);   // 16 MB [E][I][H]
  unsigned short* wut  = (unsigned short*)(ws + 20971520);  // 16 MB [E][I][H]
  unsigned short* wdt2 = (unsigned short*)(ws + 37748736);  // 16 MB [E][H][I]
  unsigned short* midp = (unsigned short*)(ws + 54525952);  // 16 MB [16384][512]
  float* combine       = (float*)(ws + 71303168);           // 128 KB
  int* tokslot         = (int*)(ws + 71434240);             // 128 KB
  unsigned short* idxl = (unsigned short*)(ws + 71565312);  // 64 KB
  int* counts          = (int*)(ws + 71630848);             // 64 B
  int* ebase           = (int*)(ws + 71630912);             // 64 B
  // dpk bf16 [16384][1024] = 32 MB: reuses wgt+wut (dead after gateup)
  unsigned short* dpk  = (unsigned short*)(ws + 4194304);

  k_cast_bf16<<<2048, 256, 0, stream>>>(x, xb);
  k_transpose64<<<dim3(8, 16, 16), 256, 0, stream>>>(wga, wgt, 1024, 512, 1024, 524288L);
  k_transpose64<<<dim3(8, 16, 16), 256, 0, stream>>>(wup, wut, 1024, 512, 1024, 524288L);
  k_transpose64<<<dim3(16, 8, 16), 256, 0, stream>>>(wdo, wdt2, 512, 1024, 512, 524288L);
  k_router<<<2048, 64, 0, stream>>>(x, gw, combine, logits);
  k_scan<<<16, 256, 0, stream>>>(combine, idxl, tokslot, counts);
  k_offsets<<<1, 64, 0, stream>>>(counts, ebase);
  k_gateup<<<1024, 512, 0, stream>>>(xb, wgt, wut, idxl, counts, ebase, midp);
  k_down<<<2048, 512, 0, stream>>>(midp, wdt2, counts, ebase, dpk);
  k_combine<<<2048, 128, 0, stream>>>(dpk, tokslot, ebase, combine, out);
}

// Round 7
// 151.932 us; speedup vs baseline: 1.4457x; 1.0074x over previous
//
#include <hip/hip_runtime.h>

typedef __attribute__((ext_vector_type(8))) short bf16x8;
typedef __attribute__((ext_vector_type(4))) float f32x4;
typedef __attribute__((ext_vector_type(4))) unsigned short u16x4;

// ---------------- helpers ----------------

static __device__ __forceinline__ unsigned short f2bfu(float f) {
  union { float f; unsigned u; } v; v.f = f;
  return (unsigned short)((v.u + 0x7fffu + ((v.u >> 16) & 1u)) >> 16);  // RNE
}

static __device__ __forceinline__ float bfu2f(unsigned short u) {
  union { unsigned u; float f; } v; v.u = ((unsigned)u) << 16; return v.f;
}

static __device__ __forceinline__ void gload_lds16(const void* g, void* l) {
  __builtin_amdgcn_global_load_lds(
      (const __attribute__((address_space(1))) unsigned int*)g,
      (__attribute__((address_space(3))) unsigned int*)l, 16, 0, 0);
}

// ---------------- prep: cast x to bf16 ----------------
__global__ __launch_bounds__(256) void k_cast_bf16(const float* __restrict__ in,
                                                   unsigned short* __restrict__ out) {
  int i = blockIdx.x * 256 + threadIdx.x;
  float4 v = ((const float4*)in)[i];
  u16x4 o = { f2bfu(v.x), f2bfu(v.y), f2bfu(v.z), f2bfu(v.w) };
  *(u16x4*)(out + (size_t)i * 4) = o;
}

// ---------------- prep: 64x64 vectorized transpose+convert ----------------
__global__ __launch_bounds__(256) void k_transpose64(const float* __restrict__ in,
                                                     unsigned short* __restrict__ out,
                                                     int R, int C, int ostride, long eoff) {
  __shared__ float tile[64][65];
  int z = blockIdx.z;
  int c0 = blockIdx.x * 64, r0 = blockIdx.y * 64;
  const float* src = in + (size_t)z * R * C;
  unsigned short* dst = out + (size_t)z * eoff;
  int cc = (threadIdx.x & 15) * 4, rr = threadIdx.x >> 4;
#pragma unroll
  for (int i = 0; i < 4; ++i) {
    float4 v = *(const float4*)(src + (size_t)(r0 + rr + i * 16) * C + c0 + cc);
    tile[rr + i * 16][cc + 0] = v.x; tile[rr + i * 16][cc + 1] = v.y;
    tile[rr + i * 16][cc + 2] = v.z; tile[rr + i * 16][cc + 3] = v.w;
  }
  __syncthreads();
#pragma unroll
  for (int i = 0; i < 4; ++i) {
    int oc = rr + i * 16;
    u16x4 o = { f2bfu(tile[cc + 0][oc]), f2bfu(tile[cc + 1][oc]),
                f2bfu(tile[cc + 2][oc]), f2bfu(tile[cc + 3][oc]) };
    *(u16x4*)(dst + (size_t)(c0 + oc) * ostride + r0 + cc) = o;
  }
}

// ---------------- router ----------------
__global__ __launch_bounds__(64) void k_router(const float* __restrict__ x,
                                               const float* __restrict__ gw,
                                               float* __restrict__ combine,
                                               float* __restrict__ logits) {
  int t = blockIdx.x;
  int lane = threadIdx.x;
  const float* xr = x + (size_t)t * 1024;
  float acc[16];
#pragma unroll
  for (int e = 0; e < 16; ++e) acc[e] = 0.f;
  for (int h = lane; h < 1024; h += 64) {
    float xv = xr[h];
    const float4* gr = (const float4*)(gw + (size_t)h * 16);
#pragma unroll
    for (int q = 0; q < 4; ++q) {
      float4 g4 = gr[q];
      acc[q * 4 + 0] += xv * g4.x;
      acc[q * 4 + 1] += xv * g4.y;
      acc[q * 4 + 2] += xv * g4.z;
      acc[q * 4 + 3] += xv * g4.w;
    }
  }
#pragma unroll
  for (int e = 0; e < 16; ++e) {
#pragma unroll
    for (int off = 32; off > 0; off >>= 1)
      acc[e] += __shfl_xor(acc[e], off);
  }
  if (lane < 16) logits[(size_t)t * 16 + lane] = acc[lane];

  float m = acc[0];
#pragma unroll
  for (int e = 1; e < 16; ++e) m = fmaxf(m, acc[e]);
  unsigned sel = 0u;
  for (int k = 0; k < 8; ++k) {
    float best = -3.4e38f; int bi = 0;
#pragma unroll
    for (int e = 0; e < 16; ++e)
      if (!((sel >> e) & 1u) && acc[e] > best) { best = acc[e]; bi = e; }
    sel |= 1u << bi;
  }
  float s = 0.f;
#pragma unroll
  for (int e = 0; e < 16; ++e)
    if ((sel >> e) & 1u) s += expf(acc[e] - m);
  float inv = 1.f / s;
  if (lane < 16)
    combine[(size_t)t * 16 + lane] = ((sel >> lane) & 1u) ? expf(acc[lane] - m) * inv : 0.f;
}

// ---------------- scan ----------------
__global__ __launch_bounds__(256) void k_scan(const float* __restrict__ combine,
                                              unsigned short* __restrict__ idxlist,
                                              int* __restrict__ tokslot,
                                              int* __restrict__ counts) {
  __shared__ int wsum[4];
  const int e = blockIdx.x;
  const int tid = threadIdx.x;
  const int lane = tid & 63, w = tid >> 6;
  const int t0 = tid * 8;
  int flags = 0, cnt = 0;
#pragma unroll
  for (int j = 0; j < 8; ++j) {
    float c = combine[(size_t)(t0 + j) * 16 + e];
    if (c != 0.f) { flags |= 1 << j; ++cnt; }
  }
  int scan = cnt;
#pragma unroll
  for (int off = 1; off < 64; off <<= 1) {
    int v = __shfl_up(scan, off);
    if (lane >= off) scan += v;
  }
  if (lane == 63) wsum[w] = scan;
  __syncthreads();
  int base = 0;
  for (int i = 0; i < w; ++i) base += wsum[i];
  int pos = base + scan - cnt;
  for (int j = 0; j < 8; ++j) {
    if ((flags >> j) & 1) {
      idxlist[e * 2048 + pos] = (unsigned short)(t0 + j);
      tokslot[(t0 + j) * 16 + e] = pos;
      ++pos;
    } else {
      tokslot[(t0 + j) * 16 + e] = -1;
    }
  }
  if (tid == 255) counts[e] = base + scan;
}

// ---------------- offsets ----------------
__global__ __launch_bounds__(64) void k_offsets(const int* __restrict__ counts,
                                                int* __restrict__ ebase) {
  int lane = threadIdx.x;
  int c = (lane < 16) ? counts[lane] : 0;
  int s = c;
#pragma unroll
  for (int off = 1; off < 16; off <<= 1) {
    int v = __shfl_up(s, off);
    if (lane >= off) s += v;
  }
  if (lane < 16) ebase[lane] = s - c;
}

// ---------------- sparse gather gate+up GEMM (counted-vmcnt pipeline) ----------------
// BM=256 slots, BN=64 (i), BK=32, 32 k-steps, 8 waves, 2 LDS buffers.
// Pipeline: vmcnt(3) -> barrier -> ds_read -> lgkmcnt(0) -> barrier -> restage -> MFMA.
__global__ __launch_bounds__(512) void k_gateup(const unsigned short* __restrict__ xb,
                                                const unsigned short* __restrict__ wgt,
                                                const unsigned short* __restrict__ wut,
                                                const unsigned short* __restrict__ idxlist,
                                                const int* __restrict__ counts,
                                                const int* __restrict__ ebase,
                                                unsigned short* __restrict__ midp) {
  const int lb = (int)(blockIdx.x & 7) * 128 + (int)(blockIdx.x >> 3);
  const int mt = lb & 7, it = (lb >> 3) & 7, e = lb >> 6;
  const int Ne = counts[e];
  const int m0 = mt * 256;
  if (m0 >= Ne) return;
  const int i0 = it * 64;

  __shared__ alignas(16) char lds[49152];   // 2 x (A 16K | Bg 4K | Bu 4K)

  const int tid = threadIdx.x;
  const int lane = tid & 63;
  const int w = tid >> 6;
  const int wm = (w >> 1) * 64;
  const int wn = (w & 1) * 32;
  const int gb = ebase[e];

  const int crow = lane >> 2;
  const int slog = (lane & 3) ^ ((crow >> 1) & 3);

  const unsigned short* wge = wgt + (size_t)e * (512 * 1024);
  const unsigned short* wue = wut + (size_t)e * (512 * 1024);

  // 24 chunks of 1KB/buffer: 0-15 A, 16-19 Bg, 20-23 Bu. 3 chunks per wave.
  const unsigned short* gsrc[3];
  int loff[3];
#pragma unroll
  for (int q = 0; q < 3; ++q) {
    int c = 3 * w + q;
    loff[q] = c * 1024;
    if (c < 16) {
      int slot = m0 + c * 16 + crow;
      slot = slot < Ne ? slot : Ne - 1;
      gsrc[q] = xb + (size_t)idxlist[e * 2048 + slot] * 1024 + slog * 8;
    } else if (c < 20) {
      gsrc[q] = wge + (size_t)(i0 + (c - 16) * 16 + crow) * 1024 + slog * 8;
    } else {
      gsrc[q] = wue + (size_t)(i0 + (c - 20) * 16 + crow) * 1024 + slog * 8;
    }
  }

  auto stage = [&](int buf, int k0) {
    char* base = lds + buf * 24576;
#pragma unroll
    for (int q = 0; q < 3; ++q)
      gload_lds16(gsrc[q] + k0, base + loff[q]);
  };

  const int r0 = lane & 15;
  const int gp16 = ((lane >> 4) ^ ((r0 >> 1) & 3)) << 4;
  const int aoff  = ((wm + r0) << 6) + gp16;
  const int bgoff = 16384 + ((wn + r0) << 6) + gp16;
  const int buoff = 20480 + ((wn + r0) << 6) + gp16;

  f32x4 accg[4][2], accu[4][2];
#pragma unroll
  for (int fm = 0; fm < 4; ++fm)
#pragma unroll
    for (int fn = 0; fn < 2; ++fn) {
      accg[fm][fn] = f32x4{0.f, 0.f, 0.f, 0.f};
      accu[fm][fn] = f32x4{0.f, 0.f, 0.f, 0.f};
    }

  stage(0, 0);
  stage(1, 32);
  for (int t = 0; t < 32; ++t) {
    const int cur = t & 1;
    if (t == 31) asm volatile("s_waitcnt vmcnt(0)" ::: "memory");
    else         asm volatile("s_waitcnt vmcnt(3)" ::: "memory");
    __builtin_amdgcn_s_barrier();
    const char* base = lds + cur * 24576;
    bf16x8 a[4], bg[2], bu[2];
#pragma unroll
    for (int fm = 0; fm < 4; ++fm) a[fm] = *(const bf16x8*)(base + aoff + fm * 1024);
#pragma unroll
    for (int fn = 0; fn < 2; ++fn) {
      bg[fn] = *(const bf16x8*)(base + bgoff + fn * 1024);
      bu[fn] = *(const bf16x8*)(base + buoff + fn * 1024);
    }
    asm volatile("s_waitcnt lgkmcnt(0)" ::: "memory");
    __builtin_amdgcn_sched_barrier(0);
    __builtin_amdgcn_s_barrier();                  // all reads of cur complete
    if (t + 2 < 32) stage(cur, (t + 2) * 32);      // refill cur; overlaps MFMA
    __builtin_amdgcn_s_setprio(1);
#pragma unroll
    for (int fm = 0; fm < 4; ++fm)
#pragma unroll
      for (int fn = 0; fn < 2; ++fn) {
        accg[fm][fn] = __builtin_amdgcn_mfma_f32_16x16x32_bf16(a[fm], bg[fn], accg[fm][fn], 0, 0, 0);
        accu[fm][fn] = __builtin_amdgcn_mfma_f32_16x16x32_bf16(a[fm], bu[fn], accu[fm][fn], 0, 0, 0);
      }
    __builtin_amdgcn_s_setprio(0);
  }

  const int gq = lane >> 4;
#pragma unroll
  for (int fm = 0; fm < 4; ++fm) {
#pragma unroll
    for (int jj = 0; jj < 4; ++jj) {
      int slot = m0 + wm + fm * 16 + gq * 4 + jj;
      if (slot >= Ne) continue;
#pragma unroll
      for (int fn = 0; fn < 2; ++fn) {
        float gv = accg[fm][fn][jj];
        float uv = accu[fm][fn][jj];
        float mv = gv / (1.f + __expf(-gv)) * uv;
        midp[(size_t)(gb + slot) * 512 + i0 + wn + fn * 16 + r0] = f2bfu(mv);
      }
    }
  }
}

// ---------------- grouped down GEMM (counted-vmcnt pipeline) ----------------
// BM=256 slots, BN=64 (h), BK=32, 16 k-steps, 8 waves. Waves 0-3: 2 loads, 4-7: 3.
__global__ __launch_bounds__(512) void k_down(const unsigned short* __restrict__ midp,
                                              const unsigned short* __restrict__ wdt2,
                                              const int* __restrict__ counts,
                                              const int* __restrict__ ebase,
                                              unsigned short* __restrict__ dpk) {
  const int lb = (int)(blockIdx.x & 7) * 256 + (int)(blockIdx.x >> 3);
  const int mt = lb & 7, ht = (lb >> 3) & 15, e = lb >> 7;
  const int Ne = counts[e];
  const int m0 = mt * 256;
  if (m0 >= Ne) return;
  const int h0 = ht * 64;

  __shared__ alignas(16) char lds[40960];   // 2 x (A 16K | B 4K)

  const int tid = threadIdx.x;
  const int lane = tid & 63;
  const int w = tid >> 6;
  const int wm = (w >> 1) * 64;
  const int wn = (w & 1) * 32;
  const int gb = ebase[e];

  const int crow = lane >> 2;
  const int slog = (lane & 3) ^ ((crow >> 1) & 3);

  const unsigned short* bsrc = wdt2 + (size_t)e * (512 * 1024);

  const unsigned short* gsrcA[2];
  int loffA[2];
#pragma unroll
  for (int q = 0; q < 2; ++q) {
    int c = q * 8 + w;
    loffA[q] = c * 1024;
    int slot = m0 + c * 16 + crow;
    slot = slot < Ne ? slot : Ne - 1;
    gsrcA[q] = midp + (size_t)(gb + slot) * 512 + slog * 8;
  }
  const unsigned short* gsrcB = nullptr;
  int loffB = 0;
  if (w >= 4) {
    loffB = 16384 + (w - 4) * 1024;
    gsrcB = bsrc + (size_t)(h0 + (w - 4) * 16 + crow) * 512 + slog * 8;
  }

  auto stage = [&](int buf, int k0) {
    char* base = lds + buf * 20480;
#pragma unroll
    for (int q = 0; q < 2; ++q)
      gload_lds16(gsrcA[q] + k0, base + loffA[q]);
    if (gsrcB) gload_lds16(gsrcB + k0, base + loffB);
  };

  const int r0 = lane & 15;
  const int gp16 = ((lane >> 4) ^ ((r0 >> 1) & 3)) << 4;
  const int aoff = ((wm + r0) << 6) + gp16;
  const int boff = 16384 + ((wn + r0) << 6) + gp16;

  f32x4 acc[4][2];
#pragma unroll
  for (int fm = 0; fm < 4; ++fm)
#pragma unroll
    for (int fn = 0; fn < 2; ++fn) acc[fm][fn] = f32x4{0.f, 0.f, 0.f, 0.f};

  stage(0, 0);
  stage(1, 32);
  for (int t = 0; t < 16; ++t) {
    const int cur = t & 1;
    if (t == 15)       asm volatile("s_waitcnt vmcnt(0)" ::: "memory");
    else if (w >= 4)   asm volatile("s_waitcnt vmcnt(3)" ::: "memory");
    else               asm volatile("s_waitcnt vmcnt(2)" ::: "memory");
    __builtin_amdgcn_s_barrier();
    const char* base = lds + cur * 20480;
    bf16x8 a[4], b[2];
#pragma unroll
    for (int fm = 0; fm < 4; ++fm) a[fm] = *(const bf16x8*)(base + aoff + fm * 1024);
#pragma unroll
    for (int fn = 0; fn < 2; ++fn) b[fn] = *(const bf16x8*)(base + boff + fn * 1024);
    asm volatile("s_waitcnt lgkmcnt(0)" ::: "memory");
    __builtin_amdgcn_sched_barrier(0);
    __builtin_amdgcn_s_barrier();
    if (t + 2 < 16) stage(cur, (t + 2) * 32);
    __builtin_amdgcn_s_setprio(1);
#pragma unroll
    for (int fm = 0; fm < 4; ++fm)
#pragma unroll
      for (int fn = 0; fn < 2; ++fn)
        acc[fm][fn] = __builtin_amdgcn_mfma_f32_16x16x32_bf16(a[fm], b[fn], acc[fm][fn], 0, 0, 0);
    __builtin_amdgcn_s_setprio(0);
  }

  const int gq = lane >> 4;
#pragma unroll
  for (int fm = 0; fm < 4; ++fm)
#pragma unroll
    for (int jj = 0; jj < 4; ++jj) {
      int slot = m0 + wm + fm * 16 + gq * 4 + jj;
      if (slot >= Ne) continue;
#pragma unroll
      for (int fn = 0; fn < 2; ++fn)
        dpk[(size_t)(gb + slot) * 1024 + h0 + wn + fn * 16 + r0] = f2bfu(acc[fm][fn][jj]);
    }
}

// ---------------- combine ----------------
__global__ __launch_bounds__(128) void k_combine(const unsigned short* __restrict__ dpk,
                                                 const int* __restrict__ tokslot,
                                                 const int* __restrict__ ebase,
                                                 const float* __restrict__ combine,
                                                 float* __restrict__ out) {
  __shared__ int gsl[16];
  __shared__ float cws[16];
  const int t = blockIdx.x;
  const int tid = threadIdx.x;
  if (tid < 16) {
    int sl = tokslot[t * 16 + tid];
    gsl[tid] = (sl >= 0) ? ebase[tid] + sl : -1;
    cws[tid] = combine[(size_t)t * 16 + tid];
  }
  __syncthreads();
  float av[8];
#pragma unroll
  for (int j = 0; j < 8; ++j) av[j] = 0.f;
#pragma unroll
  for (int e = 0; e < 16; ++e) {
    int g = gsl[e];
    if (g < 0) continue;
    float cw = cws[e];
    bf16x8 v = *(const bf16x8*)(dpk + (size_t)g * 1024 + tid * 8);
#pragma unroll
    for (int j = 0; j < 8; ++j) av[j] += cw * bfu2f((unsigned short)v[j]);
  }
  float4 lo = { av[0], av[1], av[2], av[3] };
  float4 hi = { av[4], av[5], av[6], av[7] };
  float4* op = (float4*)(out + (size_t)t * 1024 + tid * 8);
  op[0] = lo;
  op[1] = hi;
}

// ---------------- launch ----------------
extern "C" void kernel_launch(void* const* d_in, const int* in_sizes, int n_in,
                              void* d_out, int out_size, void* d_ws, size_t ws_size,
                              hipStream_t stream) {
  const float* x   = (const float*)d_in[0];
  const float* gw  = (const float*)d_in[1];
  const float* wga = (const float*)d_in[2];
  const float* wup = (const float*)d_in[3];
  const float* wdo = (const float*)d_in[4];
  float* out = (float*)d_out;
  float* logits = out + (size_t)2048 * 1024;

  char* ws = (char*)d_ws;
  unsigned short* xb   = (unsigned short*)(ws + 0);         //  4 MB
  unsigned short* wgt  = (unsigned short*)(ws + 4194304);   // 16 MB [E][I][H]
  unsigned short* wut  = (unsigned short*)(ws + 20971520);  // 16 MB [E][I][H]
  unsigned short* wdt2 = (unsigned short*)(ws + 37748736);  // 16 MB [E][H][I]
  unsigned short* midp = (unsigned short*)(ws + 54525952);  // 16 MB [16384][512]
  float* combine       = (float*)(ws + 71303168);           // 128 KB
  int* tokslot         = (int*)(ws + 71434240);             // 128 KB
  unsigned short* idxl = (unsigned short*)(ws + 71565312);  // 64 KB
  int* counts          = (int*)(ws + 71630848);             // 64 B
  int* ebase           = (int*)(ws + 71630912);             // 64 B
  unsigned short* dpk  = (unsigned short*)(ws + 4194304);   // 32 MB, reuses wgt+wut

  k_cast_bf16<<<2048, 256, 0, stream>>>(x, xb);
  k_transpose64<<<dim3(8, 16, 16), 256, 0, stream>>>(wga, wgt, 1024, 512, 1024, 524288L);
  k_transpose64<<<dim3(8, 16, 16), 256, 0, stream>>>(wup, wut, 1024, 512, 1024, 524288L);
  k_transpose64<<<dim3(16, 8, 16), 256, 0, stream>>>(wdo, wdt2, 512, 1024, 512, 524288L);
  k_router<<<2048, 64, 0, stream>>>(x, gw, combine, logits);
  k_scan<<<16, 256, 0, stream>>>(combine, idxl, tokslot, counts);
  k_offsets<<<1, 64, 0, stream>>>(counts, ebase);
  k_gateup<<<1024, 512, 0, stream>>>(xb, wgt, wut, idxl, counts, ebase, midp);
  k_down<<<2048, 512, 0, stream>>>(midp, wdt2, counts, ebase, dpk);
  k_combine<<<2048, 128, 0, stream>>>(dpk, tokslot, ebase, combine, out);
}